// Round 2
// baseline (250.328 us; speedup 1.0000x reference)
//
#include <hip/hip_runtime.h>
#include <hip/hip_bf16.h>
#include <math.h>

#define B_ 2
#define L_ 4096
#define E_ 1024
#define H_ 16
#define D_ 64
#define CK_ 64
#define NC_ 64

typedef __bf16 bf16x8 __attribute__((ext_vector_type(8)));
typedef __bf16 bf16x4 __attribute__((ext_vector_type(4)));
typedef float  f32x4  __attribute__((ext_vector_type(4)));

__device__ __forceinline__ float fmap1(float x) { return x > 0.f ? x + 1.f : expf(x); }
__device__ __forceinline__ float b2f(__bf16 v) {
    __hip_bfloat16 h = *reinterpret_cast<__hip_bfloat16*>(&v); return __bfloat162float(h);
}
__device__ __forceinline__ __bf16 f2b(float f) {
    __hip_bfloat16 h = __float2bfloat16(f); return *reinterpret_cast<__bf16*>(&h);
}
__device__ __forceinline__ unsigned short f2u(float f) {
    __hip_bfloat16 h = __float2bfloat16(f); return *reinterpret_cast<unsigned short*>(&h);
}

union U8 { bf16x8 v; __bf16 e[8]; bf16x4 half2[2]; };

__device__ __forceinline__ void async16(const __bf16* g, __bf16* lds) {
    __builtin_amdgcn_global_load_lds(
        (const __attribute__((address_space(1))) void*)g,
        (__attribute__((address_space(3))) void*)lds, 16, 0, 0);
}

// ---------------------------------------------------------------------------
__global__ __launch_bounds__(256) void cast_f32_bf16(const float* __restrict__ in,
                                                     __hip_bfloat16* __restrict__ out, int n) {
    int i = (blockIdx.x * 256 + threadIdx.x) << 2;
    if (i < n) {
        float4 v = *(const float4*)(in + i);
        ushort4 o = {f2u(v.x), f2u(v.y), f2u(v.z), f2u(v.w)};
        *(ushort4*)(out + i) = o;
    }
}

// ---------------------------------------------------------------------------
// 256x256 / BK=64 / 8-wave (2Mx4N) 4x(2-quadrant)-phase GEMM, fused qkv epi.
// Per K-tile t (buffers buf[t&1]):
//   p1 q(0,0): LDA(q0)+LDB(q0) | stage (t+1).A-q1 -> buf^1
//   p2 q(0,1): LDB(q1)         | stage (t+2).B-q0 -> buf
//   p3 q(1,0): LDA(q1)         | stage (t+2).B-q1 -> buf
//   p4 q(1,1): -               | stage (t+2).A-q0 -> buf, vmcnt(6)
// Each phase: reads|stage, barrier, lgkmcnt(0), setprio(1), 16 MFMA,
// setprio(0), [counted vmcnt], barrier.  vmcnt(6) leaves 3 half-tiles
// (6 calls) in flight; every subtile lands >=1 guarded barrier before use
// and every LDS overwrite is issued >=1 barrier after that region's last read.
// st_16x32 swizzle: LDS dest linear; global SOURCE pre-swizzled with the
// same involution as the ds_read side (rule #21).
// ---------------------------------------------------------------------------
__global__ __launch_bounds__(512, 2) void gemm256_qkv(const __bf16* __restrict__ A,
                                                      const __bf16* __restrict__ Bw,
                                                      __hip_bfloat16* __restrict__ C,
                                                      __hip_bfloat16* __restrict__ KT,
                                                      __hip_bfloat16* __restrict__ VT,
                                                      int M, int N, int K) {
    __shared__ alignas(16) __bf16 ldsA[2][16384];
    __shared__ alignas(16) __bf16 ldsB[2][16384];
    const int tid  = threadIdx.x;
    const int wave = tid >> 6, lane = tid & 63;
    const int wm = wave >> 2, wn = wave & 3;
    const int lq = lane >> 4, lr = lane & 15;
    const int m0 = blockIdx.y << 8, n0 = blockIdx.x << 8;
    const int NT = K >> 6;

    f32x4 acc[8][4];
#pragma unroll
    for (int i = 0; i < 8; ++i)
#pragma unroll
        for (int j = 0; j < 4; ++j) acc[i][j] = (f32x4){0.f, 0.f, 0.f, 0.f};

    // ---- staging geometry: per-lane pre-swizzled global source ----
    const int srow = lane >> 2;                                  // row in 16x32 subtile
    const int scol = ((lane & 3) << 3) ^ ((lane >> 5) << 4);     // swizzled col (elems)
    const __bf16* Ab0 = A  + (size_t)(m0 + wm * 128 + wn * 16 + srow) * K + scol; // A-q0 own
    const __bf16* Ab1 = Ab0 + (size_t)64 * K;                                     // A-q1 own
    const __bf16* Bb0 = Bw + (size_t)(n0 + wn * 64 + wm * 16 + srow) * K + scol;  // B-q0 own
    const __bf16* Bb1 = Bb0 + (size_t)32 * K;                                     // B-q1 own
    // LDS pair bases (elements): pair = 16 rows x 64 cols = 1024 elems
    const int saoff0 = (wm * 8 + wn) << 10;
    const int saoff1 = (wm * 8 + 4 + wn) << 10;
    const int sboff0 = (wn * 4 + wm) << 10;
    const int sboff1 = (wn * 4 + 2 + wm) << 10;

#define STG_A0(bufi, kt) do { const __bf16* g_ = Ab0 + ((size_t)(kt) << 6); \
    async16(g_,      &ldsA[bufi][saoff0]); \
    async16(g_ + 32, &ldsA[bufi][saoff0 + 512]); } while (0)
#define STG_A1(bufi, kt) do { const __bf16* g_ = Ab1 + ((size_t)(kt) << 6); \
    async16(g_,      &ldsA[bufi][saoff1]); \
    async16(g_ + 32, &ldsA[bufi][saoff1 + 512]); } while (0)
#define STG_B0(bufi, kt) do { const __bf16* g_ = Bb0 + ((size_t)(kt) << 6); \
    async16(g_,      &ldsB[bufi][sboff0]); \
    async16(g_ + 32, &ldsB[bufi][sboff0 + 512]); } while (0)
#define STG_B1(bufi, kt) do { const __bf16* g_ = Bb1 + ((size_t)(kt) << 6); \
    async16(g_,      &ldsB[bufi][sboff1]); \
    async16(g_ + 32, &ldsB[bufi][sboff1 + 512]); } while (0)

    // in-subtile byte for ds_read fragments (same involution as scol)
    const int inn = (lr << 6) + ((lq << 4) ^ ((lr & 8) << 2));
    bf16x8 af[4][2], bfr[2][2][2];

#define LDA(qm) { const char* p_ = (const char*)ldsA[cur]; \
    _Pragma("unroll") for (int mt = 0; mt < 4; ++mt) \
    _Pragma("unroll") for (int ks = 0; ks < 2; ++ks) \
        af[mt][ks] = *(const bf16x8*)(p_ + ((((wm * 8 + (qm) * 4 + mt) << 1) + ks) << 10) + inn); }
#define LDB(qn) { const char* p_ = (const char*)ldsB[cur]; \
    _Pragma("unroll") for (int nt = 0; nt < 2; ++nt) \
    _Pragma("unroll") for (int ks = 0; ks < 2; ++ks) \
        bfr[qn][nt][ks] = *(const bf16x8*)(p_ + ((((wn * 4 + (qn) * 2 + nt) << 1) + ks) << 10) + inn); }
#define MM(qm, qn) { \
    _Pragma("unroll") for (int mt = 0; mt < 4; ++mt) \
    _Pragma("unroll") for (int nt = 0; nt < 2; ++nt) { \
        acc[(qm)*4+mt][(qn)*2+nt] = __builtin_amdgcn_mfma_f32_16x16x32_bf16( \
            af[mt][0], bfr[qn][nt][0], acc[(qm)*4+mt][(qn)*2+nt], 0, 0, 0); \
        acc[(qm)*4+mt][(qn)*2+nt] = __builtin_amdgcn_mfma_f32_16x16x32_bf16( \
            af[mt][1], bfr[qn][nt][1], acc[(qm)*4+mt][(qn)*2+nt], 0, 0, 0); } }
#define BAR() __builtin_amdgcn_s_barrier()
#define WLG0() do { asm volatile("s_waitcnt lgkmcnt(0)" ::: "memory"); \
    __builtin_amdgcn_sched_barrier(0); } while (0)
#define WVM(n) do { asm volatile("s_waitcnt vmcnt(" #n ")" ::: "memory"); \
    __builtin_amdgcn_sched_barrier(0); } while (0)

    // ---- prologue: tile0 complete + tile1 {Bq0,Bq1,Aq0} in flight ----
    STG_B0(0, 0); STG_B1(0, 0); STG_A0(0, 0); STG_A1(0, 0);
    STG_B0(1, 1); STG_B1(1, 1); STG_A0(1, 1);
    WVM(6);
    BAR();

    for (int t = 0; t < NT; ++t) {
        const int cur = t & 1;
        // ---- phase 1: quadrant (0,0) ----
        LDA(0); LDB(0);
        if (t + 1 < NT) STG_A1(cur ^ 1, t + 1);
        BAR();
        WLG0();
        __builtin_amdgcn_s_setprio(1);
        MM(0, 0);
        __builtin_amdgcn_s_setprio(0);
        BAR();
        // ---- phase 2: quadrant (0,1) ----
        LDB(1);
        if (t + 2 < NT) STG_B0(cur, t + 2);
        BAR();
        WLG0();
        __builtin_amdgcn_s_setprio(1);
        MM(0, 1);
        __builtin_amdgcn_s_setprio(0);
        BAR();
        // ---- phase 3: quadrant (1,0) ----
        LDA(1);
        if (t + 2 < NT) STG_B1(cur, t + 2);
        BAR();
        WLG0();
        __builtin_amdgcn_s_setprio(1);
        MM(1, 0);
        __builtin_amdgcn_s_setprio(0);
        BAR();
        // ---- phase 4: quadrant (1,1) ----
        if (t + 2 < NT) STG_A0(cur, t + 2);
        BAR();
        __builtin_amdgcn_s_setprio(1);
        MM(1, 1);
        __builtin_amdgcn_s_setprio(0);
        if (t < NT - 2)       { WVM(6); }
        else if (t == NT - 2) { WVM(0); }
        BAR();
    }

    // ---- fused qkv epilogue (w uniform per block since 256 | 1024) ----
    const int w = n0 >> 10;
#pragma unroll
    for (int i = 0; i < 8; ++i) {
        const int m = m0 + wm * 128 + i * 16 + lq * 4;
        const int bb = m >> 12, l = m & 4095;
#pragma unroll
        for (int j = 0; j < 4; ++j) {
            const int n = n0 + wn * 64 + j * 16 + lr;
            float vv[4];
#pragma unroll
            for (int r = 0; r < 4; ++r) {
                float v = acc[i][j][r];
                if (w == 0)      v = fmap1(v) * 0.125f;
                else if (w == 1) v = fmap1(v);
                vv[r] = v;
                C[(size_t)(m + r) * N + n] = __float2bfloat16(v);
            }
            if (w >= 1) {   // transposed copies: w1 -> KT, w2 -> VT
                const int hh = (n >> 6) & 15, dd = n & 63;
                __hip_bfloat16* T = (w == 1) ? KT : VT;
                ushort4 u = {f2u(vv[0]), f2u(vv[1]), f2u(vv[2]), f2u(vv[3])};
                *(ushort4*)&T[((size_t)((bb * 16 + hh) * 64 + dd) << 12) + l] = u;
            }
        }
    }
#undef STG_A0
#undef STG_A1
#undef STG_B0
#undef STG_B1
#undef LDA
#undef LDB
#undef MM
#undef BAR
#undef WLG0
#undef WVM
}

// ---------------------------------------------------------------------------
// Old 128x128 MFMA GEMM (kept for out = attn @ Wout^T; N=1024 would leave
// half the chip idle at 256^2 tiles).
// ---------------------------------------------------------------------------
template<int EPI>
__global__ __launch_bounds__(256) void gemm_mfma(const __bf16* __restrict__ A,
                                                 const __bf16* __restrict__ Bw,
                                                 void* __restrict__ Cv,
                                                 __hip_bfloat16* __restrict__ KT,
                                                 __hip_bfloat16* __restrict__ VT,
                                                 int M, int N, int K) {
    __shared__ alignas(16) __bf16 As[128 * 32];
    __shared__ alignas(16) __bf16 Bs[128 * 32];
    const int tid = threadIdx.x;
    const int wave = tid >> 6, lane = tid & 63;
    const int wm = wave >> 1, wn = wave & 1;
    const int lq = lane >> 4, lr = lane & 15;
    const int m0 = blockIdx.y * 128, n0 = blockIdx.x * 128;

    f32x4 acc[4][4];
#pragma unroll
    for (int i = 0; i < 4; ++i)
#pragma unroll
        for (int j = 0; j < 4; ++j) acc[i][j] = (f32x4){0.f, 0.f, 0.f, 0.f};

    const int stg_r = lane >> 2, stg_c = (lane & 3) << 3;
    const __bf16* Ag0 = A + (size_t)(m0 + (wave << 4) + stg_r) * K + stg_c;
    const __bf16* Ag1 = A + (size_t)(m0 + 64 + (wave << 4) + stg_r) * K + stg_c;
    const __bf16* Bg0 = Bw + (size_t)(n0 + (wave << 4) + stg_r) * K + stg_c;
    const __bf16* Bg1 = Bw + (size_t)(n0 + 64 + (wave << 4) + stg_r) * K + stg_c;
    __bf16* Al0 = As + (wave << 9);
    __bf16* Al1 = As + ((wave + 4) << 9);
    __bf16* Bl0 = Bs + (wave << 9);
    __bf16* Bl1 = Bs + ((wave + 4) << 9);

    for (int kt = 0; kt < K; kt += 32) {
        __syncthreads();
        async16(Ag0 + kt, Al0);
        async16(Ag1 + kt, Al1);
        async16(Bg0 + kt, Bl0);
        async16(Bg1 + kt, Bl1);
        __syncthreads();
        bf16x8 af[4], bfr[4];
#pragma unroll
        for (int t = 0; t < 4; ++t) {
            af[t]  = *(const bf16x8*)&As[((wm << 6) + (t << 4) + lr) * 32 + (lq << 3)];
            bfr[t] = *(const bf16x8*)&Bs[((wn << 6) + (t << 4) + lr) * 32 + (lq << 3)];
        }
#pragma unroll
        for (int mt = 0; mt < 4; ++mt)
#pragma unroll
            for (int nt = 0; nt < 4; ++nt)
                acc[mt][nt] = __builtin_amdgcn_mfma_f32_16x16x32_bf16(
                    af[mt], bfr[nt], acc[mt][nt], 0, 0, 0);
    }

#pragma unroll
    for (int mt = 0; mt < 4; ++mt) {
#pragma unroll
        for (int nt = 0; nt < 4; ++nt) {
            int m = m0 + (wm << 6) + (mt << 4) + (lq << 2);
            int n = n0 + (wn << 6) + (nt << 4) + lr;
            if (EPI == 1) {
                int w = n >> 10, hh = (n >> 6) & 15, dd = n & 63;
                float vv[4];
#pragma unroll
                for (int r = 0; r < 4; ++r) {
                    float v = acc[mt][nt][r];
                    if (w == 0)      v = fmap1(v) * 0.125f;
                    else if (w == 1) v = fmap1(v);
                    vv[r] = v;
                    ((__hip_bfloat16*)Cv)[(size_t)(m + r) * N + n] = __float2bfloat16(v);
                }
                if (w >= 1) {
                    int b = m >> 12, l = m & 4095;
                    __hip_bfloat16* T = (w == 1) ? KT : VT;
                    ushort4 u = {f2u(vv[0]), f2u(vv[1]), f2u(vv[2]), f2u(vv[3])};
                    *(ushort4*)&T[((size_t)((b * 16 + hh) * 64 + dd) << 12) + l] = u;
                }
            } else {
#pragma unroll
                for (int r = 0; r < 4; ++r)
                    ((float*)Cv)[(size_t)(m + r) * N + n] = acc[mt][nt][r];
            }
        }
    }
}

// ---------------------------------------------------------------------------
// MFMA per-chunk state: S_T[e][d] = sum_l VT[e][l]*KT[d][l]; Z[d] = sum_l KT[d][l].
// grid (16, 32); wave = chunk c = bx*4+w. Stores bf16.
// ---------------------------------------------------------------------------
__global__ __launch_bounds__(256) void chunk_state_mfma(const __hip_bfloat16* __restrict__ KTh,
                                                        const __hip_bfloat16* __restrict__ VTh,
                                                        __hip_bfloat16* __restrict__ Sb,
                                                        __hip_bfloat16* __restrict__ Zb) {
    const int tid = threadIdx.x, wave = tid >> 6, lane = tid & 63;
    const int quad = lane >> 4, lr = lane & 15;
    const int bh = blockIdx.y;
    const int c = blockIdx.x * 4 + wave;
    const __bf16* KT = (const __bf16*)KTh;
    const __bf16* VT = (const __bf16*)VTh;

    bf16x8 vt[4][2], kt[4][2];
#pragma unroll
    for (int t = 0; t < 4; ++t)
#pragma unroll
        for (int kk = 0; kk < 2; ++kk) {
            size_t rowoff = ((size_t)(bh * 64 + t * 16 + lr) << 12) + c * CK_ + kk * 32 + quad * 8;
            vt[t][kk] = *(const bf16x8*)&VT[rowoff];
            kt[t][kk] = *(const bf16x8*)&KT[rowoff];
        }

    U8 of;
#pragma unroll
    for (int j = 0; j < 8; ++j) of.e[j] = f2b(1.0f);

    __hip_bfloat16* Sp = Sb + ((size_t)(c * 32 + bh) << 12);
#pragma unroll
    for (int es = 0; es < 4; ++es) {
#pragma unroll
        for (int dt = 0; dt < 4; ++dt) {
            f32x4 acc = (f32x4){0.f, 0.f, 0.f, 0.f};
            acc = __builtin_amdgcn_mfma_f32_16x16x32_bf16(vt[es][0], kt[dt][0], acc, 0, 0, 0);
            acc = __builtin_amdgcn_mfma_f32_16x16x32_bf16(vt[es][1], kt[dt][1], acc, 0, 0, 0);
#pragma unroll
            for (int r = 0; r < 4; ++r)
                Sp[(es * 16 + quad * 4 + r) * 64 + dt * 16 + lr] =
                    __float2bfloat16(acc[r]);
        }
    }
#pragma unroll
    for (int dt = 0; dt < 4; ++dt) {
        f32x4 z = (f32x4){0.f, 0.f, 0.f, 0.f};
        z = __builtin_amdgcn_mfma_f32_16x16x32_bf16(kt[dt][0], of.v, z, 0, 0, 0);
        z = __builtin_amdgcn_mfma_f32_16x16x32_bf16(kt[dt][1], of.v, z, 0, 0, 0);
        if (lr == 0) {
#pragma unroll
            for (int r = 0; r < 4; ++r)
                Zb[((c * 32 + bh) << 6) + dt * 16 + quad * 4 + r] = __float2bfloat16(z[r]);
        }
    }
}

// ---------------------------------------------------------------------------
// In-place exclusive prefix over 64 chunks on bf16 states, f32 carry.
// grid (16, 32).
// ---------------------------------------------------------------------------
__global__ __launch_bounds__(256) void prefix64(__hip_bfloat16* __restrict__ Sb,
                                                __hip_bfloat16* __restrict__ Zb) {
    const int bh = blockIdx.y;
    const int idx = blockIdx.x * 256 + threadIdx.x;   // 0..4095
    float run = 0.f;
    for (int c = 0; c < NC_; ++c) {
        size_t off = ((size_t)(c * 32 + bh) << 12) + idx;
        float cur = __bfloat162float(Sb[off]);
        Sb[off] = __float2bfloat16(run);
        run += cur;
    }
    if (blockIdx.x == 0 && threadIdx.x < 64) {
        float zr = 0.f;
        for (int c = 0; c < NC_; ++c) {
            int zoff = ((c * 32 + bh) << 6) + threadIdx.x;
            float cz = __bfloat162float(Zb[zoff]);
            Zb[zoff] = __float2bfloat16(zr);
            zr += cz;
        }
    }
}

// ---------------------------------------------------------------------------
// MFMA attention output (R8-verified structure; S/Z bf16 vector loads).
// ---------------------------------------------------------------------------
__global__ __launch_bounds__(256) void attn_out_mfma(const __hip_bfloat16* __restrict__ qvh,
                                                     const __hip_bfloat16* __restrict__ Sbh,
                                                     const __hip_bfloat16* __restrict__ Zbh,
                                                     const __hip_bfloat16* __restrict__ VTh,
                                                     __hip_bfloat16* __restrict__ attn) {
    __shared__ __bf16 Pbuf[4 * 64 * 68];
    const int tid = threadIdx.x, wave = tid >> 6, lane = tid & 63;
    const int quad = lane >> 4, lr = lane & 15;
    const int bh = blockIdx.y, b = bh >> 4, h = bh & 15;
    const int c = blockIdx.x * 4 + wave;
    const size_t t0 = (size_t)b * L_ + c * CK_;
    const __bf16* qb = (const __bf16*)qvh;
    const __bf16* Sb = (const __bf16*)Sbh;
    const __bf16* Zb = (const __bf16*)Zbh;
    const __bf16* VT = (const __bf16*)VTh;
    __bf16* P = Pbuf + wave * (64 * 68);

    bf16x8 qf[4][2];
#pragma unroll
    for (int ls = 0; ls < 4; ++ls)
#pragma unroll
        for (int kk = 0; kk < 2; ++kk)
            qf[ls][kk] = *(const bf16x8*)&qb[(t0 + ls * 16 + lr) * 3072 + h * 64 + kk * 32 + quad * 8];

    f32x4 num[4][4], den[4];
#pragma unroll
    for (int i = 0; i < 4; ++i) {
        den[i] = (f32x4){0.f, 0.f, 0.f, 0.f};
#pragma unroll
        for (int j = 0; j < 4; ++j) num[i][j] = (f32x4){0.f, 0.f, 0.f, 0.f};
    }

    bf16x8 zf[2];
#pragma unroll
    for (int kk = 0; kk < 2; ++kk)
        zf[kk] = *(const bf16x8*)&Zb[((size_t)(c * 32 + bh) << 6) + kk * 32 + quad * 8];
#pragma unroll
    for (int ls = 0; ls < 4; ++ls)
#pragma unroll
        for (int kk = 0; kk < 2; ++kk)
            den[ls] = __builtin_amdgcn_mfma_f32_16x16x32_bf16(qf[ls][kk], zf[kk], den[ls], 0, 0, 0);

#pragma unroll
    for (int es = 0; es < 4; ++es) {
        bf16x8 sf[2];
#pragma unroll
        for (int kk = 0; kk < 2; ++kk)
            sf[kk] = *(const bf16x8*)&Sb[((size_t)(c * 32 + bh) << 12)
                                         + (es * 16 + lr) * 64 + kk * 32 + quad * 8];
#pragma unroll
        for (int ls = 0; ls < 4; ++ls)
#pragma unroll
            for (int kk = 0; kk < 2; ++kk)
                num[ls][es] = __builtin_amdgcn_mfma_f32_16x16x32_bf16(
                    qf[ls][kk], sf[kk], num[ls][es], 0, 0, 0);
    }

    bf16x8 kf[4][2];
#pragma unroll
    for (int ms = 0; ms < 4; ++ms)
#pragma unroll
        for (int kk = 0; kk < 2; ++kk)
            kf[ms][kk] = *(const bf16x8*)&qb[(t0 + ms * 16 + lr) * 3072 + 1024 + h * 64 + kk * 32 + quad * 8];

#pragma unroll
    for (int ls = 0; ls < 4; ++ls) {
#pragma unroll
        for (int ms = 0; ms < 4; ++ms) {
            int off = (ls * 16 + lr) * 68 + ms * 16 + quad * 4;
            if (ms <= ls) {
                f32x4 pt = (f32x4){0.f, 0.f, 0.f, 0.f};
                pt = __builtin_amdgcn_mfma_f32_16x16x32_bf16(kf[ms][0], qf[ls][0], pt, 0, 0, 0);
                pt = __builtin_amdgcn_mfma_f32_16x16x32_bf16(kf[ms][1], qf[ls][1], pt, 0, 0, 0);
                ushort4 u;
                if (ms == ls) {
                    u.x = (quad * 4 + 0 > lr) ? 0 : f2u(pt[0]);
                    u.y = (quad * 4 + 1 > lr) ? 0 : f2u(pt[1]);
                    u.z = (quad * 4 + 2 > lr) ? 0 : f2u(pt[2]);
                    u.w = (quad * 4 + 3 > lr) ? 0 : f2u(pt[3]);
                } else {
                    u = (ushort4){f2u(pt[0]), f2u(pt[1]), f2u(pt[2]), f2u(pt[3])};
                }
                *(ushort4*)&P[off] = u;
            } else {
                *(ushort4*)&P[off] = (ushort4){0, 0, 0, 0};
            }
        }
    }

    U8 of;
#pragma unroll
    for (int j = 0; j < 8; ++j) of.e[j] = f2b(1.0f);

#pragma unroll
    for (int kk = 0; kk < 2; ++kk) {
        U8 pf[4];
#pragma unroll
        for (int ls = 0; ls < 4; ++ls) {
            pf[ls].half2[0] = *(const bf16x4*)&P[(ls * 16 + lr) * 68 + kk * 32 + quad * 8];
            pf[ls].half2[1] = *(const bf16x4*)&P[(ls * 16 + lr) * 68 + kk * 32 + quad * 8 + 4];
        }
        bf16x8 vf[4];
#pragma unroll
        for (int es = 0; es < 4; ++es)
            vf[es] = *(const bf16x8*)&VT[((size_t)((b * 16 + h) * 64 + es * 16 + lr) << 12)
                                         + c * CK_ + kk * 32 + quad * 8];
#pragma unroll
        for (int ls = 0; ls < 4; ++ls) {
            den[ls] = __builtin_amdgcn_mfma_f32_16x16x32_bf16(pf[ls].v, of.v, den[ls], 0, 0, 0);
#pragma unroll
            for (int es = 0; es < 4; ++es)
                num[ls][es] = __builtin_amdgcn_mfma_f32_16x16x32_bf16(
                    pf[ls].v, vf[es], num[ls][es], 0, 0, 0);
        }
    }

#pragma unroll
    for (int ls = 0; ls < 4; ++ls) {
#pragma unroll
        for (int r = 0; r < 4; ++r) {
            float inv = 1.f / fmaxf(den[ls][r], 1e-6f);
            size_t row = (t0 + ls * 16 + quad * 4 + r) * 1024 + h * 64;
#pragma unroll
            for (int es = 0; es < 4; ++es)
                attn[row + es * 16 + lr] = __float2bfloat16(num[ls][es][r] * inv);
        }
    }
}

// ---------------------------------------------------------------------------
extern "C" void kernel_launch(void* const* d_in, const int* in_sizes, int n_in,
                              void* d_out, int out_size, void* d_ws, size_t ws_size,
                              hipStream_t stream) {
    (void)ws_size; (void)out_size;
    const float *x = nullptr, *Wqkv = nullptr, *Wout = nullptr;
    for (int i = 0; i < n_in; ++i) {
        if (in_sizes[i] == 8388608)      x    = (const float*)d_in[i];
        else if (in_sizes[i] == 3145728) Wqkv = (const float*)d_in[i];
        else if (in_sizes[i] == 1048576) Wout = (const float*)d_in[i];
    }

    __hip_bfloat16* ws16  = (__hip_bfloat16*)d_ws;
    __hip_bfloat16* xb    = ws16;                       //  8388608 (attn aliases)
    __hip_bfloat16* attn  = ws16;
    __hip_bfloat16* Wqkvb = ws16 + 8388608;             //  3145728
    __hip_bfloat16* Woutb = Wqkvb + 3145728;            //  1048576
    __hip_bfloat16* qv    = Woutb + 1048576;            // 25165824
    __hip_bfloat16* VT    = qv + 25165824;              //  8388608
    __hip_bfloat16* KT    = VT + 8388608;               //  8388608
    __hip_bfloat16* Sb    = KT + 8388608;               //  8388608
    __hip_bfloat16* Zb    = Sb + 8388608;               //   131072

    cast_f32_bf16<<<8388608 / 1024, 256, 0, stream>>>(x, xb, 8388608);
    cast_f32_bf16<<<3145728 / 1024, 256, 0, stream>>>(Wqkv, Wqkvb, 3145728);
    cast_f32_bf16<<<1048576 / 1024, 256, 0, stream>>>(Wout, Woutb, 1048576);

    // 1. qv (+KT,+VT) = feature_map(xb @ Wqkvb^T)  — 256^2 4-phase template
    gemm256_qkv<<<dim3(3072 / 256, 8192 / 256), 512, 0, stream>>>(
        (const __bf16*)xb, (const __bf16*)Wqkvb, qv, KT, VT, B_ * L_, 3 * E_, E_);
    // 2. per-chunk states via MFMA (bf16 out)
    chunk_state_mfma<<<dim3(16, B_ * H_), 256, 0, stream>>>(KT, VT, Sb, Zb);
    // 3. exclusive prefix over 64 chunks (in-place bf16, f32 carry)
    prefix64<<<dim3(16, B_ * H_), 256, 0, stream>>>(Sb, Zb);
    // 4. MFMA attention output -> attn bf16
    attn_out_mfma<<<dim3(16, B_ * H_), 256, 0, stream>>>(qv, Sb, Zb, VT, attn);
    // 5. out = attn @ Woutb^T, f32 (old 128^2 kernel; N=1024 too small for 256^2 grid)
    gemm_mfma<0><<<dim3(1024 / 128, 8192 / 128), 256, 0, stream>>>(
        (const __bf16*)attn, (const __bf16*)Woutb, d_out, nullptr, nullptr, B_ * L_, E_, E_);
}

// Round 4
// 244.362 us; speedup vs baseline: 1.0244x; 1.0244x over previous
//
#include <hip/hip_runtime.h>
#include <hip/hip_bf16.h>
#include <math.h>

#define B_ 2
#define L_ 4096
#define E_ 1024
#define H_ 16
#define D_ 64
#define CK_ 64
#define NC_ 64

typedef __bf16 bf16x8 __attribute__((ext_vector_type(8)));
typedef __bf16 bf16x4 __attribute__((ext_vector_type(4)));
typedef float  f32x4  __attribute__((ext_vector_type(4)));

__device__ __forceinline__ float fmap1(float x) { return x > 0.f ? x + 1.f : expf(x); }
__device__ __forceinline__ float b2f(__bf16 v) {
    __hip_bfloat16 h = *reinterpret_cast<__hip_bfloat16*>(&v); return __bfloat162float(h);
}
__device__ __forceinline__ __bf16 f2b(float f) {
    __hip_bfloat16 h = __float2bfloat16(f); return *reinterpret_cast<__bf16*>(&h);
}
__device__ __forceinline__ unsigned short f2u(float f) {
    __hip_bfloat16 h = __float2bfloat16(f); return *reinterpret_cast<unsigned short*>(&h);
}

union U8 { bf16x8 v; __bf16 e[8]; bf16x4 half2[2]; };

__device__ __forceinline__ void async16(const __bf16* g, __bf16* lds) {
    __builtin_amdgcn_global_load_lds(
        (const __attribute__((address_space(1))) void*)g,
        (__attribute__((address_space(3))) void*)lds, 16, 0, 0);
}

// ---------------------------------------------------------------------------
__global__ __launch_bounds__(256) void cast_f32_bf16(const float* __restrict__ in,
                                                     __hip_bfloat16* __restrict__ out, int n) {
    int i = (blockIdx.x * 256 + threadIdx.x) << 2;
    if (i < n) {
        float4 v = *(const float4*)(in + i);
        ushort4 o = {f2u(v.x), f2u(v.y), f2u(v.z), f2u(v.w)};
        *(ushort4*)(out + i) = o;
    }
}

// ---------------------------------------------------------------------------
// MFMA bf16 GEMM: C = A*Bw^T. 128x128 tile, BK=32, 4 waves 2x2, 4x4 16x16x32.
// Staging discipline (the single change vs the 92.6us baseline):
//   3 LDS buffers (48 KiB -> still 3 blocks/CU), distance-2 prefetch,
//   counted s_waitcnt vmcnt(4) (never 0 in loop), ONE raw s_barrier/step.
// Ledger (4 async16 calls/wave/step): end of step t, outstanding =
// {stage(t+1), stage(t+2)} = 8; vmcnt(4) forces stage(t+1) complete while
// stage(t+2) stays in flight across the barrier.  stage(t+2) writes
// buf[(t+2)%3] == buf[(t-1)%3], whose reads were sealed by barrier(t-1).
// EPI=1: qkv epilogue (w0: q~=fmap*0.125, w1: k~=fmap, w2: v) bf16 +
// transposed KT (w1) / VT (w2). EPI=0: plain f32 store.
// ---------------------------------------------------------------------------
#define WVMC(n) do { asm volatile("s_waitcnt vmcnt(" #n ")" ::: "memory"); \
    __builtin_amdgcn_sched_barrier(0); } while (0)

template<int EPI>
__global__ __launch_bounds__(256) void gemm_mfma3(const __bf16* __restrict__ A,
                                                  const __bf16* __restrict__ Bw,
                                                  void* __restrict__ Cv,
                                                  __hip_bfloat16* __restrict__ KT,
                                                  __hip_bfloat16* __restrict__ VT,
                                                  int M, int N, int K) {
    __shared__ alignas(16) __bf16 As[3][128 * 32];
    __shared__ alignas(16) __bf16 Bs[3][128 * 32];
    const int tid = threadIdx.x;
    const int wave = tid >> 6, lane = tid & 63;
    const int wm = wave >> 1, wn = wave & 1;
    const int lq = lane >> 4, lr = lane & 15;
    const int m0 = blockIdx.y * 128, n0 = blockIdx.x * 128;
    const int NS = K >> 5;

    f32x4 acc[4][4];
#pragma unroll
    for (int i = 0; i < 4; ++i)
#pragma unroll
        for (int j = 0; j < 4; ++j) acc[i][j] = (f32x4){0.f, 0.f, 0.f, 0.f};

    const int stg_r = lane >> 2, stg_c = (lane & 3) << 3;
    const __bf16* Ag0 = A + (size_t)(m0 + (wave << 4) + stg_r) * K + stg_c;
    const __bf16* Ag1 = A + (size_t)(m0 + 64 + (wave << 4) + stg_r) * K + stg_c;
    const __bf16* Bg0 = Bw + (size_t)(n0 + (wave << 4) + stg_r) * K + stg_c;
    const __bf16* Bg1 = Bw + (size_t)(n0 + 64 + (wave << 4) + stg_r) * K + stg_c;
    const int dl0 = (wave << 9), dl1 = ((wave + 4) << 9);  // per-wave LDS dest (elems)

#define STG3(bi, t) do { const int ko_ = (t) << 5; \
    async16(Ag0 + ko_, &As[bi][dl0]); \
    async16(Ag1 + ko_, &As[bi][dl1]); \
    async16(Bg0 + ko_, &Bs[bi][dl0]); \
    async16(Bg1 + ko_, &Bs[bi][dl1]); } while (0)

    // prologue: fill buf0, buf1; force buf0 (leave buf1's 4 calls in flight)
    STG3(0, 0);
    STG3(1, 1);
    WVMC(4);
    __builtin_amdgcn_s_barrier();

    int bi = 0, bn = 2;           // bi: compute buffer; bn: dest for stage(t+2)
    for (int t = 0; t < NS; ++t) {
        if (t + 2 < NS) STG3(bn, t + 2);
        bf16x8 af[4], bfr[4];
#pragma unroll
        for (int tt = 0; tt < 4; ++tt) {
            af[tt]  = *(const bf16x8*)&As[bi][((wm << 6) + (tt << 4) + lr) * 32 + (lq << 3)];
            bfr[tt] = *(const bf16x8*)&Bs[bi][((wn << 6) + (tt << 4) + lr) * 32 + (lq << 3)];
        }
#pragma unroll
        for (int mt = 0; mt < 4; ++mt)
#pragma unroll
            for (int nt = 0; nt < 4; ++nt)
                acc[mt][nt] = __builtin_amdgcn_mfma_f32_16x16x32_bf16(
                    af[mt], bfr[nt], acc[mt][nt], 0, 0, 0);
        if (t < NS - 2)       { WVMC(4); }   // force stage(t+1); keep stage(t+2) in flight
        else if (t == NS - 2) { WVMC(0); }   // last prefetch must land
        __builtin_amdgcn_s_barrier();
        bi = (bi == 2) ? 0 : bi + 1;
        bn = (bn == 2) ? 0 : bn + 1;
    }

#pragma unroll
    for (int mt = 0; mt < 4; ++mt) {
#pragma unroll
        for (int nt = 0; nt < 4; ++nt) {
            int m = m0 + (wm << 6) + (mt << 4) + (lq << 2);
            int n = n0 + (wn << 6) + (nt << 4) + lr;
            if (EPI == 1) {
                int w = n >> 10, hh = (n >> 6) & 15, dd = n & 63;
                float vv[4];
#pragma unroll
                for (int r = 0; r < 4; ++r) {
                    float v = acc[mt][nt][r];
                    if (w == 0)      v = fmap1(v) * 0.125f;
                    else if (w == 1) v = fmap1(v);
                    vv[r] = v;
                    ((__hip_bfloat16*)Cv)[(size_t)(m + r) * N + n] = __float2bfloat16(v);
                }
                if (w >= 1) {   // transposed copies: w1 -> KT, w2 -> VT
                    int b = m >> 12, l = m & 4095;
                    __hip_bfloat16* T = (w == 1) ? KT : VT;
                    ushort4 u = {f2u(vv[0]), f2u(vv[1]), f2u(vv[2]), f2u(vv[3])};
                    *(ushort4*)&T[((size_t)((b * 16 + hh) * 64 + dd) << 12) + l] = u;
                }
            } else {
#pragma unroll
                for (int r = 0; r < 4; ++r)
                    ((float*)Cv)[(size_t)(m + r) * N + n] = acc[mt][nt][r];
            }
        }
    }
#undef STG3
}

// ---------------------------------------------------------------------------
// MFMA per-chunk state: S_T[e][d] = sum_l VT[e][l]*KT[d][l]; Z[d] = sum_l KT[d][l].
// grid (16, 32); wave = chunk c = bx*4+w. Stores bf16.
// ---------------------------------------------------------------------------
__global__ __launch_bounds__(256) void chunk_state_mfma(const __hip_bfloat16* __restrict__ KTh,
                                                        const __hip_bfloat16* __restrict__ VTh,
                                                        __hip_bfloat16* __restrict__ Sb,
                                                        __hip_bfloat16* __restrict__ Zb) {
    const int tid = threadIdx.x, wave = tid >> 6, lane = tid & 63;
    const int quad = lane >> 4, lr = lane & 15;
    const int bh = blockIdx.y;
    const int c = blockIdx.x * 4 + wave;
    const __bf16* KT = (const __bf16*)KTh;
    const __bf16* VT = (const __bf16*)VTh;

    bf16x8 vt[4][2], kt[4][2];
#pragma unroll
    for (int t = 0; t < 4; ++t)
#pragma unroll
        for (int kk = 0; kk < 2; ++kk) {
            size_t rowoff = ((size_t)(bh * 64 + t * 16 + lr) << 12) + c * CK_ + kk * 32 + quad * 8;
            vt[t][kk] = *(const bf16x8*)&VT[rowoff];
            kt[t][kk] = *(const bf16x8*)&KT[rowoff];
        }

    U8 of;
#pragma unroll
    for (int j = 0; j < 8; ++j) of.e[j] = f2b(1.0f);

    __hip_bfloat16* Sp = Sb + ((size_t)(c * 32 + bh) << 12);
#pragma unroll
    for (int es = 0; es < 4; ++es) {
#pragma unroll
        for (int dt = 0; dt < 4; ++dt) {
            f32x4 acc = (f32x4){0.f, 0.f, 0.f, 0.f};
            acc = __builtin_amdgcn_mfma_f32_16x16x32_bf16(vt[es][0], kt[dt][0], acc, 0, 0, 0);
            acc = __builtin_amdgcn_mfma_f32_16x16x32_bf16(vt[es][1], kt[dt][1], acc, 0, 0, 0);
#pragma unroll
            for (int r = 0; r < 4; ++r)
                Sp[(es * 16 + quad * 4 + r) * 64 + dt * 16 + lr] =
                    __float2bfloat16(acc[r]);
        }
    }
#pragma unroll
    for (int dt = 0; dt < 4; ++dt) {
        f32x4 z = (f32x4){0.f, 0.f, 0.f, 0.f};
        z = __builtin_amdgcn_mfma_f32_16x16x32_bf16(kt[dt][0], of.v, z, 0, 0, 0);
        z = __builtin_amdgcn_mfma_f32_16x16x32_bf16(kt[dt][1], of.v, z, 0, 0, 0);
        if (lr == 0) {
#pragma unroll
            for (int r = 0; r < 4; ++r)
                Zb[((c * 32 + bh) << 6) + dt * 16 + quad * 4 + r] = __float2bfloat16(z[r]);
        }
    }
}

// ---------------------------------------------------------------------------
// In-place exclusive prefix over 64 chunks on bf16 states, f32 carry.
// grid (16, 32).
// ---------------------------------------------------------------------------
__global__ __launch_bounds__(256) void prefix64(__hip_bfloat16* __restrict__ Sb,
                                                __hip_bfloat16* __restrict__ Zb) {
    const int bh = blockIdx.y;
    const int idx = blockIdx.x * 256 + threadIdx.x;   // 0..4095
    float run = 0.f;
    for (int c = 0; c < NC_; ++c) {
        size_t off = ((size_t)(c * 32 + bh) << 12) + idx;
        float cur = __bfloat162float(Sb[off]);
        Sb[off] = __float2bfloat16(run);
        run += cur;
    }
    if (blockIdx.x == 0 && threadIdx.x < 64) {
        float zr = 0.f;
        for (int c = 0; c < NC_; ++c) {
            int zoff = ((c * 32 + bh) << 6) + threadIdx.x;
            float cz = __bfloat162float(Zb[zoff]);
            Zb[zoff] = __float2bfloat16(zr);
            zr += cz;
        }
    }
}

// ---------------------------------------------------------------------------
// MFMA attention output (R8-verified structure; S/Z bf16 vector loads).
// ---------------------------------------------------------------------------
__global__ __launch_bounds__(256) void attn_out_mfma(const __hip_bfloat16* __restrict__ qvh,
                                                     const __hip_bfloat16* __restrict__ Sbh,
                                                     const __hip_bfloat16* __restrict__ Zbh,
                                                     const __hip_bfloat16* __restrict__ VTh,
                                                     __hip_bfloat16* __restrict__ attn) {
    __shared__ __bf16 Pbuf[4 * 64 * 68];
    const int tid = threadIdx.x, wave = tid >> 6, lane = tid & 63;
    const int quad = lane >> 4, lr = lane & 15;
    const int bh = blockIdx.y, b = bh >> 4, h = bh & 15;
    const int c = blockIdx.x * 4 + wave;
    const size_t t0 = (size_t)b * L_ + c * CK_;
    const __bf16* qb = (const __bf16*)qvh;
    const __bf16* Sb = (const __bf16*)Sbh;
    const __bf16* Zb = (const __bf16*)Zbh;
    const __bf16* VT = (const __bf16*)VTh;
    __bf16* P = Pbuf + wave * (64 * 68);

    bf16x8 qf[4][2];
#pragma unroll
    for (int ls = 0; ls < 4; ++ls)
#pragma unroll
        for (int kk = 0; kk < 2; ++kk)
            qf[ls][kk] = *(const bf16x8*)&qb[(t0 + ls * 16 + lr) * 3072 + h * 64 + kk * 32 + quad * 8];

    f32x4 num[4][4], den[4];
#pragma unroll
    for (int i = 0; i < 4; ++i) {
        den[i] = (f32x4){0.f, 0.f, 0.f, 0.f};
#pragma unroll
        for (int j = 0; j < 4; ++j) num[i][j] = (f32x4){0.f, 0.f, 0.f, 0.f};
    }

    bf16x8 zf[2];
#pragma unroll
    for (int kk = 0; kk < 2; ++kk)
        zf[kk] = *(const bf16x8*)&Zb[((size_t)(c * 32 + bh) << 6) + kk * 32 + quad * 8];
#pragma unroll
    for (int ls = 0; ls < 4; ++ls)
#pragma unroll
        for (int kk = 0; kk < 2; ++kk)
            den[ls] = __builtin_amdgcn_mfma_f32_16x16x32_bf16(qf[ls][kk], zf[kk], den[ls], 0, 0, 0);

#pragma unroll
    for (int es = 0; es < 4; ++es) {
        bf16x8 sf[2];
#pragma unroll
        for (int kk = 0; kk < 2; ++kk)
            sf[kk] = *(const bf16x8*)&Sb[((size_t)(c * 32 + bh) << 12)
                                         + (es * 16 + lr) * 64 + kk * 32 + quad * 8];
#pragma unroll
        for (int ls = 0; ls < 4; ++ls)
#pragma unroll
            for (int kk = 0; kk < 2; ++kk)
                num[ls][es] = __builtin_amdgcn_mfma_f32_16x16x32_bf16(
                    qf[ls][kk], sf[kk], num[ls][es], 0, 0, 0);
    }

    bf16x8 kf[4][2];
#pragma unroll
    for (int ms = 0; ms < 4; ++ms)
#pragma unroll
        for (int kk = 0; kk < 2; ++kk)
            kf[ms][kk] = *(const bf16x8*)&qb[(t0 + ms * 16 + lr) * 3072 + 1024 + h * 64 + kk * 32 + quad * 8];

#pragma unroll
    for (int ls = 0; ls < 4; ++ls) {
#pragma unroll
        for (int ms = 0; ms < 4; ++ms) {
            int off = (ls * 16 + lr) * 68 + ms * 16 + quad * 4;
            if (ms <= ls) {
                f32x4 pt = (f32x4){0.f, 0.f, 0.f, 0.f};
                pt = __builtin_amdgcn_mfma_f32_16x16x32_bf16(kf[ms][0], qf[ls][0], pt, 0, 0, 0);
                pt = __builtin_amdgcn_mfma_f32_16x16x32_bf16(kf[ms][1], qf[ls][1], pt, 0, 0, 0);
                ushort4 u;
                if (ms == ls) {
                    u.x = (quad * 4 + 0 > lr) ? 0 : f2u(pt[0]);
                    u.y = (quad * 4 + 1 > lr) ? 0 : f2u(pt[1]);
                    u.z = (quad * 4 + 2 > lr) ? 0 : f2u(pt[2]);
                    u.w = (quad * 4 + 3 > lr) ? 0 : f2u(pt[3]);
                } else {
                    u = (ushort4){f2u(pt[0]), f2u(pt[1]), f2u(pt[2]), f2u(pt[3])};
                }
                *(ushort4*)&P[off] = u;
            } else {
                *(ushort4*)&P[off] = (ushort4){0, 0, 0, 0};
            }
        }
    }

    U8 of;
#pragma unroll
    for (int j = 0; j < 8; ++j) of.e[j] = f2b(1.0f);

#pragma unroll
    for (int kk = 0; kk < 2; ++kk) {
        U8 pf[4];
#pragma unroll
        for (int ls = 0; ls < 4; ++ls) {
            pf[ls].half2[0] = *(const bf16x4*)&P[(ls * 16 + lr) * 68 + kk * 32 + quad * 8];
            pf[ls].half2[1] = *(const bf16x4*)&P[(ls * 16 + lr) * 68 + kk * 32 + quad * 8 + 4];
        }
        bf16x8 vf[4];
#pragma unroll
        for (int es = 0; es < 4; ++es)
            vf[es] = *(const bf16x8*)&VT[((size_t)((b * 16 + h) * 64 + es * 16 + lr) << 12)
                                         + c * CK_ + kk * 32 + quad * 8];
#pragma unroll
        for (int ls = 0; ls < 4; ++ls) {
            den[ls] = __builtin_amdgcn_mfma_f32_16x16x32_bf16(pf[ls].v, of.v, den[ls], 0, 0, 0);
#pragma unroll
            for (int es = 0; es < 4; ++es)
                num[ls][es] = __builtin_amdgcn_mfma_f32_16x16x32_bf16(
                    pf[ls].v, vf[es], num[ls][es], 0, 0, 0);
        }
    }

#pragma unroll
    for (int ls = 0; ls < 4; ++ls) {
#pragma unroll
        for (int r = 0; r < 4; ++r) {
            float inv = 1.f / fmaxf(den[ls][r], 1e-6f);
            size_t row = (t0 + ls * 16 + quad * 4 + r) * 1024 + h * 64;
#pragma unroll
            for (int es = 0; es < 4; ++es)
                attn[row + es * 16 + lr] = __float2bfloat16(num[ls][es][r] * inv);
        }
    }
}

// ---------------------------------------------------------------------------
extern "C" void kernel_launch(void* const* d_in, const int* in_sizes, int n_in,
                              void* d_out, int out_size, void* d_ws, size_t ws_size,
                              hipStream_t stream) {
    (void)ws_size; (void)out_size;
    const float *x = nullptr, *Wqkv = nullptr, *Wout = nullptr;
    for (int i = 0; i < n_in; ++i) {
        if (in_sizes[i] == 8388608)      x    = (const float*)d_in[i];
        else if (in_sizes[i] == 3145728) Wqkv = (const float*)d_in[i];
        else if (in_sizes[i] == 1048576) Wout = (const float*)d_in[i];
    }

    __hip_bfloat16* ws16  = (__hip_bfloat16*)d_ws;
    __hip_bfloat16* xb    = ws16;                       //  8388608 (attn aliases)
    __hip_bfloat16* attn  = ws16;
    __hip_bfloat16* Wqkvb = ws16 + 8388608;             //  3145728
    __hip_bfloat16* Woutb = Wqkvb + 3145728;            //  1048576
    __hip_bfloat16* qv    = Woutb + 1048576;            // 25165824
    __hip_bfloat16* VT    = qv + 25165824;              //  8388608
    __hip_bfloat16* KT    = VT + 8388608;               //  8388608
    __hip_bfloat16* Sb    = KT + 8388608;               //  8388608
    __hip_bfloat16* Zb    = Sb + 8388608;               //   131072

    cast_f32_bf16<<<8388608 / 1024, 256, 0, stream>>>(x, xb, 8388608);
    cast_f32_bf16<<<3145728 / 1024, 256, 0, stream>>>(Wqkv, Wqkvb, 3145728);
    cast_f32_bf16<<<1048576 / 1024, 256, 0, stream>>>(Wout, Woutb, 1048576);

    // 1. qv (+KT,+VT) = feature_map(xb @ Wqkvb^T)  — 3-buf counted-vmcnt
    gemm_mfma3<1><<<dim3(3072 / 128, 8192 / 128), 256, 0, stream>>>(
        (const __bf16*)xb, (const __bf16*)Wqkvb, qv, KT, VT, B_ * L_, 3 * E_, E_);
    // 2. per-chunk states via MFMA (bf16 out)
    chunk_state_mfma<<<dim3(16, B_ * H_), 256, 0, stream>>>(KT, VT, Sb, Zb);
    // 3. exclusive prefix over 64 chunks (in-place bf16, f32 carry)
    prefix64<<<dim3(16, B_ * H_), 256, 0, stream>>>(Sb, Zb);
    // 4. MFMA attention output -> attn bf16
    attn_out_mfma<<<dim3(16, B_ * H_), 256, 0, stream>>>(qv, Sb, Zb, VT, attn);
    // 5. out = attn @ Woutb^T, f32 — same 3-buf counted-vmcnt template
    gemm_mfma3<0><<<dim3(1024 / 128, 8192 / 128), 256, 0, stream>>>(
        (const __bf16*)attn, (const __bf16*)Woutb, d_out, nullptr, nullptr, B_ * L_, E_, E_);
}